// Round 12
// baseline (3917.616 us; speedup 1.0000x reference)
//
#include <hip/hip_runtime.h>
#include <hip/hip_bf16.h>
#include <math.h>

#pragma clang fp contract(off)

#define BB   32
#define DIN  100
#define HH   256
#define NLAY 4
#define NH   32
#define LL   4096
#define LC   128
#define NC   32
#define HL   (HH*LL)   // 1048576
#define BLn  (BB*LL)   // 131072

typedef __attribute__((ext_vector_type(8))) short s8v;
typedef __attribute__((ext_vector_type(4))) float f4v;

__device__ inline unsigned short f2b(float x) {
    unsigned int u = __float_as_uint(x);
    unsigned int r = (u + 0x7fffu + ((u >> 16) & 1u)) >> 16;
    return (unsigned short)r;
}
__device__ inline float b2f(unsigned short u) {
    return __uint_as_float(((unsigned int)u) << 16);
}

// ---------------- encoder (MFMA) + flag zeroing ----------------
__global__ __launch_bounds__(256) void k_enc(const float* __restrict__ x,
                                             const float* __restrict__ ew,
                                             unsigned short* __restrict__ hb,
                                             int* __restrict__ flags) {
    __shared__ unsigned short xs[BB*128];
    __shared__ unsigned short ot[BB*264];
    int tid = threadIdx.x;
    if (blockIdx.x == 0 && tid < 128) flags[tid] = 0;   // zero producer/consumer counters
    for (int idx = tid; idx < BB*128; idx += 256) {
        int b = idx >> 7, k = idx & 127;
        float v = (k < DIN) ? x[b*DIN + k] : 0.f;
        int slot = (k >> 3) ^ (b & 7);
        xs[b*128 + slot*8 + (k & 7)] = f2b(v);
    }
    __syncthreads();
    int hl0 = blockIdx.x * 256;
    int h = hl0 >> 12, l0 = hl0 & 4095;
    int w = tid >> 6, l = tid & 63;
    int l16 = l & 15, lk8 = (l >> 4) * 8, e4 = (l >> 4) * 4;
    int col0 = w * 64;
    f4v acc[2][4];
    #pragma unroll
    for (int i = 0; i < 2; i++)
        #pragma unroll
        for (int j = 0; j < 4; j++) acc[i][j] = (f4v){0.f,0.f,0.f,0.f};
    #pragma unroll
    for (int ks = 0; ks < 4; ks++) {
        int kb = ks*32 + lk8;
        int sl0 = kb >> 3;
        s8v a0 = *(const s8v*)&xs[l16*128 + (sl0 ^ (l16 & 7))*8];
        s8v a1 = *(const s8v*)&xs[(16 + l16)*128 + (sl0 ^ (l16 & 7))*8];
        #pragma unroll
        for (int j = 0; j < 4; j++) {
            int hl = hl0 + col0 + j*16 + l16;
            const float* ep = ew + (size_t)kb * HL + hl;
            s8v bf;
            #pragma unroll
            for (int q = 0; q < 8; q++) {
                float ev = (kb + q < DIN) ? ep[(size_t)q * HL] : 0.f;
                bf[q] = (short)f2b(ev);
            }
            acc[0][j] = __builtin_amdgcn_mfma_f32_16x16x32_bf16(a0, bf, acc[0][j], 0, 0, 0);
            acc[1][j] = __builtin_amdgcn_mfma_f32_16x16x32_bf16(a1, bf, acc[1][j], 0, 0, 0);
        }
    }
    #pragma unroll
    for (int i = 0; i < 2; i++)
        #pragma unroll
        for (int j = 0; j < 4; j++) {
            int cl = col0 + j*16 + l16;
            #pragma unroll
            for (int e = 0; e < 4; e++) {
                int b = i*16 + e4 + e;
                ot[b*264 + cl] = f2b(acc[i][j][e]);
            }
        }
    __syncthreads();
    {
        int b = tid >> 3, off = (tid & 7) * 32;
        const unsigned short* src = &ot[b*264 + off];
        unsigned short* dst = &hb[(size_t)h*BLn + (size_t)b*LL + l0 + off];
        #pragma unroll
        for (int q = 0; q < 4; q++)
            *(s8v*)(dst + q*8) = *(const s8v*)(src + q*8);
    }
}

// ---------------- parameter precompute (ALL layers) ----------------
__global__ __launch_bounds__(256) void k_prep1(const float* __restrict__ ldt,
        const float* __restrict__ Cp, const float* __restrict__ lAr,
        const float* __restrict__ Aimp,
        float* __restrict__ pdta, float* __restrict__ pwlc, float* __restrict__ pcd2) {
    int g = blockIdx.x*256 + threadIdx.x;
    int layer = g >> 13, h = (g >> 5) & 255, n = g & 31;
    float dt  = expf(ldt[layer*HH + h]);
    float are = -expf(lAr[(layer*HH + h)*NH + n]);
    float aim = Aimp[(layer*HH + h)*NH + n];
    float dre = are*dt, dimg = aim*dt;
    float er = expf(dre);
    float s, c; sincosf(dimg, &s, &c);
    float wre = er*c, wim = er*s;
    float den = are*are + aim*aim;
    float nre = wre - 1.f, nim = wim;
    float qre = (nre*are + nim*aim)/den;
    float qim = (nim*are - nre*aim)/den;
    float cre = Cp[((layer*HH + h)*NH + n)*2 + 0];
    float cim = Cp[((layer*HH + h)*NH + n)*2 + 1];
    float dcr = cre*qre - cim*qim;
    float dci = cre*qim + cim*qre;
    pcd2[g*2+0] = 2.f*dcr;  pcd2[g*2+1] = 2.f*dci;
    pdta[g*2+0] = dre;      pdta[g*2+1] = dimg;
    float erl = expf(dre*(float)LC);
    float sl, cl; sincosf(dimg*(float)LC, &sl, &cl);
    pwlc[g*2+0] = erl*cl;   pwlc[g*2+1] = erl*sl;
}

// ---------------- merged builder ----------------
__global__ __launch_bounds__(256) void k_bldAll(const float* __restrict__ pdta,
        const float* __restrict__ pcd2, unsigned short* __restrict__ AstB,
        unsigned short* __restrict__ AcvB) {
    __shared__ float dre_s[NH], dim_s[NH], c2r[NH], c2i[NH];
    __shared__ float kkl[LC];
    int bid = blockIdx.x;
    int tid = threadIdx.x;
    int pbase = bid * 64;
    if (tid < NH) {
        dre_s[tid] = pdta[pbase + tid*2];
        dim_s[tid] = pdta[pbase + tid*2 + 1];
        c2r[tid]   = pcd2[pbase + tid*2];
        c2i[tid]   = pcd2[pbase + tid*2 + 1];
    }
    __syncthreads();
    if (tid < LC) {
        float fm = (float)tid;
        float acc = 0.f;
        for (int n = 0; n < NH; n++) {
            float er = expf(dre_s[n]*fm);
            float s, c; sincosf(dim_s[n]*fm, &s, &c);
            acc += c2r[n]*er*c - c2i[n]*er*s;
        }
        kkl[tid] = acc;
    }
    __syncthreads();
    unsigned short* As = AstB + (size_t)bid * 8192;
    for (int idx = tid; idx < 8192; idx += 256) {
        int r = idx >> 7, m = idx & 127, n = r >> 1;
        float e = (float)(127 - m);
        float er = expf(dre_s[n]*e);
        float s, c; sincosf(dim_s[n]*e, &s, &c);
        As[idx] = f2b((r & 1) ? er*s : er*c);
    }
    unsigned short* Ac = AcvB + (size_t)bid * 24576;
    for (int idx = tid; idx < 24576; idx += 256) {
        int j = idx / 192, k = idx - j*192;
        float v;
        if (k < 128) {
            v = (j >= k) ? kkl[j - k] : 0.f;
        } else {
            int n = (k - 128) >> 1;
            float e = (float)(j + 1);
            float er = expf(dre_s[n]*e);
            float s, c; sincosf(dim_s[n]*e, &s, &c);
            v = ((k - 128) & 1) ? (-er*s) : (er*c);
        }
        Ac[idx] = f2b(v);
    }
}

__global__ __launch_bounds__(256) void k_prepW(const float* __restrict__ outw,
                                               unsigned short* __restrict__ Wbf) {
    int t = blockIdx.x*256 + threadIdx.x;
    Wbf[t] = f2b(outw[t]);
}

// ---------------- device helpers for the mega kernel ----------------
__device__ __forceinline__ void waitflag(int* p, int target) {
    if (threadIdx.x == 0) {
        while (__hip_atomic_load(p, __ATOMIC_RELAXED, __HIP_MEMORY_SCOPE_AGENT) < target)
            __builtin_amdgcn_s_sleep(2);
    }
    __syncthreads();
    __threadfence();   // acquire: invalidate stale cached lines before data reads
}

// BG tile (64 cols), R11 code verbatim on a 256-thread half-block
__device__ __forceinline__ void bg_tile(unsigned short* Ul, unsigned short* Fl,
        const unsigned short* AstL, const unsigned short* AcvL,
        const unsigned short* hb, const float* pwlcL, const float* pcd2L,
        const float* DskL, unsigned short* Ybf, int h, int ct, int tid) {
    __syncthreads();   // protect LDS reuse from previous tile/phase
    const unsigned short* ub = hb + (size_t)h*BLn + (size_t)ct*64*LC;
    #pragma unroll
    for (int it = 0; it < 4; it++) {
        int idx = it*256 + tid;
        int col = idx >> 4, slot = idx & 15;
        s8v v = *(const s8v*)(ub + col*LC + slot*8);
        *(s8v*)&Ul[col*128 + (slot ^ (col & 7))*8] = v;
    }
    __syncthreads();
    int w = tid >> 6, l = tid & 63;
    int l16 = l & 15, lk8 = (l >> 4)*8, e4 = (l >> 4)*4, k8q = l >> 4;

    {   // phase A
        f4v facc[4];
        #pragma unroll
        for (int j = 0; j < 4; j++) facc[j] = (f4v){0.f,0.f,0.f,0.f};
        const unsigned short* Ab = AstL + (size_t)h*8192 + (w*16 + l16)*128;
        #pragma unroll
        for (int ks = 0; ks < 4; ks++) {
            s8v af = *(const s8v*)(Ab + ks*32 + lk8);
            int k8 = ks*4 + k8q;
            #pragma unroll
            for (int j = 0; j < 4; j++) {
                int col = j*16 + l16;
                s8v bf = *(const s8v*)&Ul[col*128 + (k8 ^ (col & 7))*8];
                facc[j] = __builtin_amdgcn_mfma_f32_16x16x32_bf16(af, bf, facc[j], 0, 0, 0);
            }
        }
        #pragma unroll
        for (int j = 0; j < 4; j++) {
            int col = j*16 + l16;
            int idx = (col*64 + w*16 + e4) ^ ((col & 7) << 3);
            *(ushort4*)&Fl[idx] = make_ushort4(f2b(facc[j][0]), f2b(facc[j][1]),
                                               f2b(facc[j][2]), f2b(facc[j][3]));
        }
    }
    __syncthreads();

    if (tid < 64) {   // chunk-prefix scan
        int n = tid & 31, bl = tid >> 5;
        int hn2 = (h*NH + n)*2;
        float wlr = pwlcL[hn2], wli = pwlcL[hn2+1];
        float cr  = pcd2L[hn2], ci  = pcd2L[hn2+1];
        float sr = 0.f, si = 0.f;
        #pragma unroll 4
        for (int c = 0; c < NC; c++) {
            int lcol = bl*32 + c;
            int idx = (lcol*64 + 2*n) ^ ((lcol & 7) << 3);
            ushort2 fv = *(ushort2*)&Fl[idx];
            float fr = b2f(fv.x), fi = b2f(fv.y);
            *(ushort2*)&Fl[idx] = make_ushort2(f2b(cr*sr - ci*si), f2b(cr*si + ci*sr));
            float nsr = fmaf(wlr, sr, fmaf(-wli, si, fr));
            si = fmaf(wlr, si, fmaf(wli, sr, fi));
            sr = nsr;
        }
    }
    __syncthreads();

    // phase B
    float dsk = DskL[h];
    const unsigned short* Cb = AcvL + (size_t)h*24576;
    f4v acc[2][4];
    #pragma unroll
    for (int i = 0; i < 2; i++)
        #pragma unroll
        for (int j = 0; j < 4; j++) acc[i][j] = (f4v){0.f,0.f,0.f,0.f};
    #pragma unroll
    for (int ks = 0; ks < 4; ks++) {
        s8v af0 = *(const s8v*)(Cb + (w*32 + l16)*192 + ks*32 + lk8);
        s8v af1 = *(const s8v*)(Cb + (w*32 + 16 + l16)*192 + ks*32 + lk8);
        int k8 = ks*4 + k8q;
        #pragma unroll
        for (int j = 0; j < 4; j++) {
            int col = j*16 + l16;
            s8v bf = *(const s8v*)&Ul[col*128 + (k8 ^ (col & 7))*8];
            acc[0][j] = __builtin_amdgcn_mfma_f32_16x16x32_bf16(af0, bf, acc[0][j], 0, 0, 0);
            acc[1][j] = __builtin_amdgcn_mfma_f32_16x16x32_bf16(af1, bf, acc[1][j], 0, 0, 0);
        }
    }
    #pragma unroll
    for (int ks = 0; ks < 2; ks++) {
        s8v af0 = *(const s8v*)(Cb + (w*32 + l16)*192 + 128 + ks*32 + lk8);
        s8v af1 = *(const s8v*)(Cb + (w*32 + 16 + l16)*192 + 128 + ks*32 + lk8);
        int kk2 = ks*32 + lk8;
        #pragma unroll
        for (int j = 0; j < 4; j++) {
            int col = j*16 + l16;
            int idx = (col*64 + kk2) ^ ((col & 7) << 3);
            s8v bf = *(const s8v*)&Fl[idx];
            acc[0][j] = __builtin_amdgcn_mfma_f32_16x16x32_bf16(af0, bf, acc[0][j], 0, 0, 0);
            acc[1][j] = __builtin_amdgcn_mfma_f32_16x16x32_bf16(af1, bf, acc[1][j], 0, 0, 0);
        }
    }
    unsigned short* Yb = Ybf + (size_t)h*BLn + (size_t)ct*64*LC;
    #pragma unroll
    for (int i = 0; i < 2; i++) {
        int m0 = w*32 + i*16 + e4;
        int sl = m0 >> 3, off = m0 & 7;
        #pragma unroll
        for (int j = 0; j < 4; j++) {
            int col = j*16 + l16;
            ushort4 u4 = *(const ushort4*)&Ul[col*128 + (sl ^ (col & 7))*8 + off];
            float uu[4] = {b2f(u4.x), b2f(u4.y), b2f(u4.z), b2f(u4.w)};
            unsigned short ov[4];
            #pragma unroll
            for (int e = 0; e < 4; e++) {
                float yv = fmaf(dsk, uu[e], acc[i][j][e]);
                ov[e] = f2b(0.5f*yv*(1.f + erff(yv*0.70710678118f)));
            }
            *(ushort4*)&Yb[col*LC + m0] = make_ushort4(ov[0], ov[1], ov[2], ov[3]);
        }
    }
}

// gC2 tile (64 n-cols), R11 code verbatim on the 512-thread block
__device__ __forceinline__ void gc2_tile(unsigned char* smem,
        const unsigned short* WbL, const float* outbL,
        const unsigned short* Ybf, unsigned short* hb, const float* dw,
        const float* db, float* outp, int nt, int doDec, int tid) {
    unsigned short* Bl = (unsigned short*)smem;
    float* part = (float*)smem;
    int n0 = nt*64;
    __syncthreads();   // protect LDS reuse
    {
        int jn = (tid & 15) * 4;
        int hq = tid >> 4;
        #pragma unroll
        for (int hb8 = 0; hb8 < 8; hb8++) {
            int h = hb8*32 + hq;
            ushort4 v = *(const ushort4*)&Ybf[(size_t)h*BLn + n0 + jn];
            unsigned short vv[4] = {v.x, v.y, v.z, v.w};
            #pragma unroll
            for (int i = 0; i < 4; i++) {
                int row = jn + i;
                Bl[row*258 + (h ^ ((row & 7) << 3))] = vv[i];
            }
        }
    }
    __syncthreads();

    int w = tid >> 6, l = tid & 63;
    int l16 = l & 15, lk8 = (l >> 4) * 8, e4 = (l >> 4) * 4;
    int ra = w*32 + l16;
    int swz = (l16 & 7) << 3;
    f4v acc[4][4];
    #pragma unroll
    for (int i = 0; i < 4; i++)
        #pragma unroll
        for (int j = 0; j < 4; j++) acc[i][j] = (f4v){0.f,0.f,0.f,0.f};
    const unsigned short* W0 = WbL + ra*HH;
    const unsigned short* W1 = WbL + (ra+16)*HH;
    const unsigned short* W2 = WbL + (ra+256)*HH;
    const unsigned short* W3 = WbL + (ra+272)*HH;
    #pragma unroll
    for (int ks = 0; ks < 8; ks++) {
        int kk = ks*32 + lk8;
        s8v a0 = *(const s8v*)(W0 + kk);
        s8v a1 = *(const s8v*)(W1 + kk);
        s8v a2 = *(const s8v*)(W2 + kk);
        s8v a3 = *(const s8v*)(W3 + kk);
        s8v bfv[4];
        #pragma unroll
        for (int j = 0; j < 4; j++) {
            int row = j*16 + l16;
            bfv[j] = *(const s8v*)&Bl[row*258 + (kk ^ swz)];
        }
        #pragma unroll
        for (int j = 0; j < 4; j++) {
            acc[0][j] = __builtin_amdgcn_mfma_f32_16x16x32_bf16(a0, bfv[j], acc[0][j], 0, 0, 0);
            acc[1][j] = __builtin_amdgcn_mfma_f32_16x16x32_bf16(a1, bfv[j], acc[1][j], 0, 0, 0);
            acc[2][j] = __builtin_amdgcn_mfma_f32_16x16x32_bf16(a2, bfv[j], acc[2][j], 0, 0, 0);
            acc[3][j] = __builtin_amdgcn_mfma_f32_16x16x32_bf16(a3, bfv[j], acc[3][j], 0, 0, 0);
        }
    }

    float pj[4] = {0.f, 0.f, 0.f, 0.f};
    #pragma unroll
    for (int i = 0; i < 2; i++) {
        int ob = w*32 + i*16 + e4;
        #pragma unroll
        for (int e = 0; e < 4; e++) {
            int o = ob + e;
            float ba  = outbL[o];
            float bb2 = outbL[o + 256];
            float dwo = doDec ? dw[o] : 0.f;
            #pragma unroll
            for (int j = 0; j < 4; j++) {
                float za = acc[i][j][e] + ba;
                float zb = acc[i+2][j][e] + bb2;
                float sig = 1.f/(1.f + expf(-zb));
                unsigned short* hp = &hb[(size_t)o*BLn + n0 + j*16 + l16];
                float hnew = fmaf(za, sig, b2f(*hp));
                if (doDec) {
                    pj[j] = fmaf(dwo, hnew, pj[j]);
                } else {
                    *hp = f2b(hnew);
                }
            }
        }
    }

    if (doDec) {
        __syncthreads();
        int g32 = w*4 + (l >> 4);
        #pragma unroll
        for (int j = 0; j < 4; j++) {
            int nl = j*16 + l16;
            part[nl*33 + g32] = pj[j];
        }
        __syncthreads();
        if (tid < 64) {
            float s = db[0];
            #pragma unroll
            for (int g = 0; g < 32; g++) s += part[tid*33 + g];
            outp[n0 + tid] = s;
        }
    }
}

// ---------------- mega kernel: full 4-layer pipeline, 16 independent batch-pair groups ----------------
__global__ __launch_bounds__(512, 4) void k_mega(
        const unsigned short* __restrict__ AstB, const unsigned short* __restrict__ AcvB,
        unsigned short* __restrict__ hb, unsigned short* __restrict__ Ybf,
        const float* __restrict__ pwlc, const float* __restrict__ pcd2,
        const float* __restrict__ Dsk, const unsigned short* __restrict__ Wbf,
        const float* __restrict__ outb, const float* __restrict__ dw,
        const float* __restrict__ db, float* __restrict__ outp,
        int* __restrict__ flags) {
    __shared__ __align__(16) unsigned char smem[49664];
    int tid = threadIdx.x;
    int g = blockIdx.x;            // 0..511
    int s = tid >> 8;              // half-block 0/1
    int tid256 = tid & 255;
    int grp = g >> 5;              // 0..15 (batch-pair group)
    unsigned short* Ul = (unsigned short*)(smem + s*24576);
    unsigned short* Fl = (unsigned short*)(smem + s*24576 + 16384);
    int* cnt1 = flags;             // [4][16]: BG -> gC2
    int* cnt2 = flags + 64;        // [4][16]: gC2 -> next BG

    for (int L = 0; L < NLAY; L++) {
        if (L) waitflag(&cnt2[(L-1)*16 + grp], 128);
        const unsigned short* AstL = AstB + (size_t)L*2097152;
        const unsigned short* AcvL = AcvB + (size_t)L*6291456;
        const float* pwlcL = pwlc + L*16384;
        const float* pcd2L = pcd2 + L*16384;
        const float* DskL  = Dsk + L*HH;
        #pragma unroll 1
        for (int i = 0; i < 4; i++) {
            int T = g*8 + s*4 + i;        // ct = T>>8 == grp for all i
            bg_tile(Ul, Fl, AstL, AcvL, hb, pwlcL, pcd2L, DskL, Ybf,
                    T & 255, T >> 8, tid256);
        }
        __threadfence();                   // release BG Y-writes
        __syncthreads();
        if (tid == 0) atomicAdd(&cnt1[L*16 + grp], 8);
        waitflag(&cnt1[L*16 + grp], 256);

        const unsigned short* WbL  = Wbf + L*131072;
        const float* outbL = outb + L*512;
        int doDec = (L == NLAY-1) ? 1 : 0;
        #pragma unroll 1
        for (int j = 0; j < 4; j++) {
            gc2_tile(smem, WbL, outbL, Ybf, hb, dw, db, outp, g*4 + j, doDec, tid);
        }
        if (L < NLAY-1) {
            __threadfence();               // release gC2 hb-writes
            __syncthreads();
            if (tid == 0) atomicAdd(&cnt2[L*16 + grp], 4);
        }
    }
}

extern "C" void kernel_launch(void* const* d_in, const int* in_sizes, int n_in,
                              void* d_out, int out_size, void* d_ws, size_t ws_size,
                              hipStream_t stream) {
    (void)in_sizes; (void)n_in; (void)out_size; (void)ws_size;
    const float* x    = (const float*)d_in[0];
    const float* ew   = (const float*)d_in[1];
    const float* ldt  = (const float*)d_in[2];
    const float* Cp   = (const float*)d_in[3];
    const float* lAr  = (const float*)d_in[4];
    const float* Aimp = (const float*)d_in[5];
    const float* Dsk  = (const float*)d_in[6];
    const float* outw = (const float*)d_in[7];
    const float* outb = (const float*)d_in[8];
    const float* dw   = (const float*)d_in[9];
    const float* db   = (const float*)d_in[10];

    float* ws = (float*)d_ws;
    unsigned short* hb  = (unsigned short*)ws;                  // 33,554,432 bf16  [h][b][l]
    unsigned short* Ybf = (unsigned short*)(ws + 16777216UL);   // 33,554,432 bf16
    unsigned short* AstB= (unsigned short*)(ws + 33554432UL);   //  8,388,608 bf16
    unsigned short* AcvB= (unsigned short*)(ws + 37748736UL);   // 25,165,824 bf16
    unsigned short* Wbf = (unsigned short*)(ws + 50331648UL);   //    524,288 bf16
    float* pdta = ws + 50593792UL;                              //     65,536 f32
    float* pwlc = ws + 50659328UL;                              //     65,536 f32
    float* pcd2 = ws + 50724864UL;                              //     65,536 f32
    int*   flg  = (int*)(ws + 50790400UL);                      //        128 i32

    k_prep1<<<128, 256, 0, stream>>>(ldt, Cp, lAr, Aimp, pdta, pwlc, pcd2);
    k_bldAll<<<1024, 256, 0, stream>>>(pdta, pcd2, AstB, AcvB);
    k_prepW<<<2048, 256, 0, stream>>>(outw, Wbf);
    k_enc<<<4096, 256, 0, stream>>>(x, ew, hb, flg);
    k_mega<<<512, 512, 0, stream>>>(AstB, AcvB, hb, Ybf, pwlc, pcd2, Dsk,
                                    Wbf, outb, dw, db, (float*)d_out, flg);
}

// Round 13
// 961.818 us; speedup vs baseline: 4.0731x; 4.0731x over previous
//
#include <hip/hip_runtime.h>
#include <hip/hip_bf16.h>
#include <math.h>

#pragma clang fp contract(off)

#define BB   32
#define DIN  100
#define HH   256
#define NLAY 4
#define NH   32
#define LL   4096
#define LC   128
#define NC   32
#define HL   (HH*LL)   // 1048576
#define BLn  (BB*LL)   // 131072

typedef __attribute__((ext_vector_type(8))) short s8v;
typedef __attribute__((ext_vector_type(4))) float f4v;

__device__ inline unsigned short f2b(float x) {
    unsigned int u = __float_as_uint(x);
    unsigned int r = (u + 0x7fffu + ((u >> 16) & 1u)) >> 16;
    return (unsigned short)r;
}
__device__ inline float b2f(unsigned short u) {
    return __uint_as_float(((unsigned int)u) << 16);
}

// ---------------- parameter precompute (ALL layers) ----------------
__global__ __launch_bounds__(256) void k_prep1(const float* __restrict__ ldt,
        const float* __restrict__ Cp, const float* __restrict__ lAr,
        const float* __restrict__ Aimp,
        float* __restrict__ pdta, float* __restrict__ pwlc, float* __restrict__ pcd2) {
    int g = blockIdx.x*256 + threadIdx.x;   // 32768 = layer*8192 + h*32 + n
    int layer = g >> 13, h = (g >> 5) & 255, n = g & 31;
    float dt  = expf(ldt[layer*HH + h]);
    float are = -expf(lAr[(layer*HH + h)*NH + n]);
    float aim = Aimp[(layer*HH + h)*NH + n];
    float dre = are*dt, dimg = aim*dt;
    float er = expf(dre);
    float s, c; sincosf(dimg, &s, &c);
    float wre = er*c, wim = er*s;
    float den = are*are + aim*aim;
    float nre = wre - 1.f, nim = wim;
    float qre = (nre*are + nim*aim)/den;
    float qim = (nim*are - nre*aim)/den;
    float cre = Cp[((layer*HH + h)*NH + n)*2 + 0];
    float cim = Cp[((layer*HH + h)*NH + n)*2 + 1];
    float dcr = cre*qre - cim*qim;
    float dci = cre*qim + cim*qre;
    pcd2[g*2+0] = 2.f*dcr;  pcd2[g*2+1] = 2.f*dci;
    pdta[g*2+0] = dre;      pdta[g*2+1] = dimg;
    float erl = expf(dre*(float)LC);
    float sl, cl; sincosf(dimg*(float)LC, &sl, &cl);
    pwlc[g*2+0] = erl*cl;   pwlc[g*2+1] = erl*sl;
}

// ---------------- merged setup: enc (blocks 0..4095) | bldAll (4096..5119) | prepW (5120..7167) ----------------
__global__ __launch_bounds__(256) void k_setup(const float* __restrict__ x,
        const float* __restrict__ ew, unsigned short* __restrict__ hb,
        const float* __restrict__ pdta, const float* __restrict__ pcd2,
        unsigned short* __restrict__ AstB, unsigned short* __restrict__ AcvB,
        const float* __restrict__ outw, unsigned short* __restrict__ Wbf) {
    __shared__ unsigned short xs[BB*128];    // enc: [b][k] bf16, swizzled, zero-padded
    __shared__ unsigned short ot[BB*264];    // enc: [b][hl_local] transpose-out buffer
    __shared__ float dre_s[NH], dim_s[NH], c2r[NH], c2i[NH];   // bldAll
    __shared__ float kkl[LC];                                   // bldAll
    int bid = blockIdx.x;
    int tid = threadIdx.x;

    if (bid >= 5120) {
        // ---- prepW: out_w (all layers) -> bf16 ----
        int t = (bid - 5120)*256 + tid;   // 0..524287
        Wbf[t] = f2b(outw[t]);
        return;
    }

    if (bid >= 4096) {
        // ---- bldAll: kker (LDS) + AstB + AcvB per (layer,h) block ----
        int bb = bid - 4096;            // layer*256 + h
        int pbase = bb * 64;
        if (tid < NH) {
            dre_s[tid] = pdta[pbase + tid*2];
            dim_s[tid] = pdta[pbase + tid*2 + 1];
            c2r[tid]   = pcd2[pbase + tid*2];
            c2i[tid]   = pcd2[pbase + tid*2 + 1];
        }
        __syncthreads();
        if (tid < LC) {
            float fm = (float)tid;
            float acc = 0.f;
            for (int n = 0; n < NH; n++) {
                float er = expf(dre_s[n]*fm);
                float s, c; sincosf(dim_s[n]*fm, &s, &c);
                acc += c2r[n]*er*c - c2i[n]*er*s;
            }
            kkl[tid] = acc;
        }
        __syncthreads();
        unsigned short* As = AstB + (size_t)bb * 8192;
        for (int idx = tid; idx < 8192; idx += 256) {
            int r = idx >> 7, m = idx & 127, n = r >> 1;
            float e = (float)(127 - m);
            float er = expf(dre_s[n]*e);
            float s, c; sincosf(dim_s[n]*e, &s, &c);
            As[idx] = f2b((r & 1) ? er*s : er*c);
        }
        unsigned short* Ac = AcvB + (size_t)bb * 24576;
        for (int idx = tid; idx < 24576; idx += 256) {
            int j = idx / 192, k = idx - j*192;
            float v;
            if (k < 128) {
                v = (j >= k) ? kkl[j - k] : 0.f;
            } else {
                int n = (k - 128) >> 1;
                float e = (float)(j + 1);
                float er = expf(dre_s[n]*e);
                float s, c; sincosf(dim_s[n]*e, &s, &c);
                v = ((k - 128) & 1) ? (-er*s) : (er*c);
            }
            Ac[idx] = f2b(v);
        }
        return;
    }

    // ---- encoder (MFMA): hb[h][b][l] = sum_i x[b][i]*ew[i][h][l] ----
    for (int idx = tid; idx < BB*128; idx += 256) {
        int b = idx >> 7, k = idx & 127;
        float v = (k < DIN) ? x[b*DIN + k] : 0.f;
        int slot = (k >> 3) ^ (b & 7);
        xs[b*128 + slot*8 + (k & 7)] = f2b(v);
    }
    __syncthreads();
    int hl0 = bid * 256;
    int h = hl0 >> 12, l0 = hl0 & 4095;
    int w = tid >> 6, l = tid & 63;
    int l16 = l & 15, lk8 = (l >> 4) * 8, e4 = (l >> 4) * 4;
    int col0 = w * 64;
    f4v acc[2][4];
    #pragma unroll
    for (int i = 0; i < 2; i++)
        #pragma unroll
        for (int j = 0; j < 4; j++) acc[i][j] = (f4v){0.f,0.f,0.f,0.f};
    #pragma unroll
    for (int ks = 0; ks < 4; ks++) {
        int kb = ks*32 + lk8;
        int sl0 = kb >> 3;
        s8v a0 = *(const s8v*)&xs[l16*128 + (sl0 ^ (l16 & 7))*8];
        s8v a1 = *(const s8v*)&xs[(16 + l16)*128 + (sl0 ^ (l16 & 7))*8];
        #pragma unroll
        for (int j = 0; j < 4; j++) {
            int hl = hl0 + col0 + j*16 + l16;
            const float* ep = ew + (size_t)kb * HL + hl;
            s8v bf;
            #pragma unroll
            for (int q = 0; q < 8; q++) {
                float ev = (kb + q < DIN) ? ep[(size_t)q * HL] : 0.f;
                bf[q] = (short)f2b(ev);
            }
            acc[0][j] = __builtin_amdgcn_mfma_f32_16x16x32_bf16(a0, bf, acc[0][j], 0, 0, 0);
            acc[1][j] = __builtin_amdgcn_mfma_f32_16x16x32_bf16(a1, bf, acc[1][j], 0, 0, 0);
        }
    }
    #pragma unroll
    for (int i = 0; i < 2; i++)
        #pragma unroll
        for (int j = 0; j < 4; j++) {
            int cl = col0 + j*16 + l16;
            #pragma unroll
            for (int e = 0; e < 4; e++) {
                int b = i*16 + e4 + e;
                ot[b*264 + cl] = f2b(acc[i][j][e]);
            }
        }
    __syncthreads();
    {
        int b = tid >> 3, off = (tid & 7) * 32;
        const unsigned short* src = &ot[b*264 + off];
        unsigned short* dst = &hb[(size_t)h*BLn + (size_t)b*LL + l0 + off];
        #pragma unroll
        for (int q = 0; q < 4; q++)
            *(s8v*)(dst + q*8) = *(const s8v*)(src + q*8);
    }
}

// ---------------- fused S4D core, 64-col tile (24 KB LDS), XCD-clustered ----------------
// grid 4096 1D: h = (g&7)*32 + (g>>7), ct = (g>>3)&15 (bijective). 256 threads = 4 waves.
__global__ __launch_bounds__(256) void k_BG(const unsigned short* __restrict__ AstB,
        const unsigned short* __restrict__ AcvB, const unsigned short* __restrict__ hb,
        const float* __restrict__ pwlc, const float* __restrict__ pcd2,
        const float* __restrict__ DskL, unsigned short* __restrict__ Ybf) {
    __shared__ unsigned short Ul[64*128];   // 16 KB [col][k] swz: slot = k8 ^ (col&7)
    __shared__ unsigned short Fl[64*64];    //  8 KB [col][r]  swz: ^((col&7)<<3)
    int g = blockIdx.x;
    int h  = (g & 7)*32 + (g >> 7);
    int ct = (g >> 3) & 15;
    int tid = threadIdx.x;
    const unsigned short* ub = hb + (size_t)h*BLn + (size_t)ct*64*LC;
    #pragma unroll
    for (int it = 0; it < 4; it++) {
        int idx = it*256 + tid;              // 1024 x 16B units
        int col = idx >> 4, slot = idx & 15;
        s8v v = *(const s8v*)(ub + col*LC + slot*8);
        *(s8v*)&Ul[col*128 + (slot ^ (col & 7))*8] = v;
    }
    __syncthreads();
    int w = tid >> 6, l = tid & 63;
    int l16 = l & 15, lk8 = (l >> 4)*8, e4 = (l >> 4)*4, k8q = l >> 4;

    // ---- phase A: F(64 x 64) = Ast(64x128) * U ; wave w owns rows w*16..+15 ----
    {
        f4v facc[4];
        #pragma unroll
        for (int j = 0; j < 4; j++) facc[j] = (f4v){0.f,0.f,0.f,0.f};
        const unsigned short* Ab = AstB + (size_t)h*8192 + (w*16 + l16)*128;
        #pragma unroll
        for (int ks = 0; ks < 4; ks++) {
            s8v af = *(const s8v*)(Ab + ks*32 + lk8);
            int k8 = ks*4 + k8q;
            #pragma unroll
            for (int j = 0; j < 4; j++) {
                int col = j*16 + l16;
                s8v bf = *(const s8v*)&Ul[col*128 + (k8 ^ (col & 7))*8];
                facc[j] = __builtin_amdgcn_mfma_f32_16x16x32_bf16(af, bf, facc[j], 0, 0, 0);
            }
        }
        #pragma unroll
        for (int j = 0; j < 4; j++) {
            int col = j*16 + l16;
            int idx = (col*64 + w*16 + e4) ^ ((col & 7) << 3);
            *(ushort4*)&Fl[idx] = make_ushort4(f2b(facc[j][0]), f2b(facc[j][1]),
                                               f2b(facc[j][2]), f2b(facc[j][3]));
        }
    }
    __syncthreads();

    // ---- chunk-prefix scan (in place: F -> T), 64 threads (32 n x 2 b) ----
    if (tid < 64) {
        int n = tid & 31, bl = tid >> 5;
        int hn2 = (h*NH + n)*2;
        float wlr = pwlc[hn2], wli = pwlc[hn2+1];
        float cr  = pcd2[hn2], ci  = pcd2[hn2+1];
        float sr = 0.f, si = 0.f;
        #pragma unroll 4
        for (int c = 0; c < NC; c++) {
            int lcol = bl*32 + c;
            int idx = (lcol*64 + 2*n) ^ ((lcol & 7) << 3);
            ushort2 fv = *(ushort2*)&Fl[idx];
            float fr = b2f(fv.x), fi = b2f(fv.y);
            *(ushort2*)&Fl[idx] = make_ushort2(f2b(cr*sr - ci*si), f2b(cr*si + ci*sr));
            float nsr = fmaf(wlr, sr, fmaf(-wli, si, fr));
            si = fmaf(wlr, si, fmaf(wli, sr, fi));
            sr = nsr;
        }
    }
    __syncthreads();

    // ---- phase B: y(128 x 64) = Acv(128x192) * [U; T] ; wave w owns rows w*32..+31 ----
    float dsk = DskL[h];
    const unsigned short* Cb = AcvB + (size_t)h*24576;
    f4v acc[2][4];
    #pragma unroll
    for (int i = 0; i < 2; i++)
        #pragma unroll
        for (int j = 0; j < 4; j++) acc[i][j] = (f4v){0.f,0.f,0.f,0.f};
    #pragma unroll
    for (int ks = 0; ks < 4; ks++) {
        s8v af0 = *(const s8v*)(Cb + (w*32 + l16)*192 + ks*32 + lk8);
        s8v af1 = *(const s8v*)(Cb + (w*32 + 16 + l16)*192 + ks*32 + lk8);
        int k8 = ks*4 + k8q;
        #pragma unroll
        for (int j = 0; j < 4; j++) {
            int col = j*16 + l16;
            s8v bf = *(const s8v*)&Ul[col*128 + (k8 ^ (col & 7))*8];
            acc[0][j] = __builtin_amdgcn_mfma_f32_16x16x32_bf16(af0, bf, acc[0][j], 0, 0, 0);
            acc[1][j] = __builtin_amdgcn_mfma_f32_16x16x32_bf16(af1, bf, acc[1][j], 0, 0, 0);
        }
    }
    #pragma unroll
    for (int ks = 0; ks < 2; ks++) {
        s8v af0 = *(const s8v*)(Cb + (w*32 + l16)*192 + 128 + ks*32 + lk8);
        s8v af1 = *(const s8v*)(Cb + (w*32 + 16 + l16)*192 + 128 + ks*32 + lk8);
        int kk2 = ks*32 + lk8;
        #pragma unroll
        for (int j = 0; j < 4; j++) {
            int col = j*16 + l16;
            int idx = (col*64 + kk2) ^ ((col & 7) << 3);
            s8v bf = *(const s8v*)&Fl[idx];
            acc[0][j] = __builtin_amdgcn_mfma_f32_16x16x32_bf16(af0, bf, acc[0][j], 0, 0, 0);
            acc[1][j] = __builtin_amdgcn_mfma_f32_16x16x32_bf16(af1, bf, acc[1][j], 0, 0, 0);
        }
    }
    // epilogue: skip (explicit fmaf) + exact GELU -> Ybf
    unsigned short* Yb = Ybf + (size_t)h*BLn + (size_t)ct*64*LC;
    #pragma unroll
    for (int i = 0; i < 2; i++) {
        int m0 = w*32 + i*16 + e4;
        int sl = m0 >> 3, off = m0 & 7;
        #pragma unroll
        for (int j = 0; j < 4; j++) {
            int col = j*16 + l16;
            ushort4 u4 = *(const ushort4*)&Ul[col*128 + (sl ^ (col & 7))*8 + off];
            float uu[4] = {b2f(u4.x), b2f(u4.y), b2f(u4.z), b2f(u4.w)};
            unsigned short ov[4];
            #pragma unroll
            for (int e = 0; e < 4; e++) {
                float yv = fmaf(dsk, uu[e], acc[i][j][e]);
                ov[e] = f2b(0.5f*yv*(1.f + erff(yv*0.70710678118f)));
            }
            *(ushort4*)&Yb[col*LC + m0] = make_ushort4(ov[0], ov[1], ov[2], ov[3]);
        }
    }
}

// ---------------- GEMM-C (MFMA): z = W*Y with in-kernel Y transpose (LDS),
//                  fused bias+GLU+residual; last layer fuses decoder ----------------
__global__ __launch_bounds__(512) void k_gC2(const unsigned short* __restrict__ Wb,
        const float* __restrict__ outb, const unsigned short* __restrict__ Ybf,
        unsigned short* __restrict__ hb, const float* __restrict__ dw,
        const float* __restrict__ db, float* __restrict__ outp, int doDec) {
    __shared__ __align__(16) unsigned char smem[34048];
    unsigned short* Bl = (unsigned short*)smem;      // [64 n][258 h], XOR-swizzled
    float* part = (float*)smem;                      // aliased: [64 n][33 groups]
    int nt = blockIdx.x;
    int n0 = nt*64;
    int tid = threadIdx.x;

    {
        int jn = (tid & 15) * 4;
        int hq = tid >> 4;          // 0..31
        #pragma unroll
        for (int hb8 = 0; hb8 < 8; hb8++) {
            int h = hb8*32 + hq;
            ushort4 v = *(const ushort4*)&Ybf[(size_t)h*BLn + n0 + jn];
            unsigned short vv[4] = {v.x, v.y, v.z, v.w};
            #pragma unroll
            for (int i = 0; i < 4; i++) {
                int row = jn + i;
                Bl[row*258 + (h ^ ((row & 7) << 3))] = vv[i];
            }
        }
    }
    __syncthreads();

    int w = tid >> 6, l = tid & 63;
    int l16 = l & 15, lk8 = (l >> 4) * 8, e4 = (l >> 4) * 4;
    int ra = w*32 + l16;
    int swz = (l16 & 7) << 3;
    f4v acc[4][4];
    #pragma unroll
    for (int i = 0; i < 4; i++)
        #pragma unroll
        for (int j = 0; j < 4; j++) acc[i][j] = (f4v){0.f,0.f,0.f,0.f};
    const unsigned short* W0 = Wb + ra*HH;
    const unsigned short* W1 = Wb + (ra+16)*HH;
    const unsigned short* W2 = Wb + (ra+256)*HH;
    const unsigned short* W3 = Wb + (ra+272)*HH;
    #pragma unroll
    for (int ks = 0; ks < 8; ks++) {
        int kk = ks*32 + lk8;
        s8v a0 = *(const s8v*)(W0 + kk);
        s8v a1 = *(const s8v*)(W1 + kk);
        s8v a2 = *(const s8v*)(W2 + kk);
        s8v a3 = *(const s8v*)(W3 + kk);
        s8v bfv[4];
        #pragma unroll
        for (int j = 0; j < 4; j++) {
            int row = j*16 + l16;
            bfv[j] = *(const s8v*)&Bl[row*258 + (kk ^ swz)];
        }
        #pragma unroll
        for (int j = 0; j < 4; j++) {
            acc[0][j] = __builtin_amdgcn_mfma_f32_16x16x32_bf16(a0, bfv[j], acc[0][j], 0, 0, 0);
            acc[1][j] = __builtin_amdgcn_mfma_f32_16x16x32_bf16(a1, bfv[j], acc[1][j], 0, 0, 0);
            acc[2][j] = __builtin_amdgcn_mfma_f32_16x16x32_bf16(a2, bfv[j], acc[2][j], 0, 0, 0);
            acc[3][j] = __builtin_amdgcn_mfma_f32_16x16x32_bf16(a3, bfv[j], acc[3][j], 0, 0, 0);
        }
    }

    float pj[4] = {0.f, 0.f, 0.f, 0.f};
    #pragma unroll
    for (int i = 0; i < 2; i++) {
        int ob = w*32 + i*16 + e4;
        #pragma unroll
        for (int e = 0; e < 4; e++) {
            int o = ob + e;
            float ba  = outb[o];
            float bb2 = outb[o + 256];
            float dwo = doDec ? dw[o] : 0.f;
            #pragma unroll
            for (int j = 0; j < 4; j++) {
                float za = acc[i][j][e] + ba;
                float zb = acc[i+2][j][e] + bb2;
                float sig = 1.f/(1.f + expf(-zb));
                unsigned short* hp = &hb[(size_t)o*BLn + n0 + j*16 + l16];
                float hnew = fmaf(za, sig, b2f(*hp));   // single rounding, pinned
                if (doDec) {
                    pj[j] = fmaf(dwo, hnew, pj[j]);
                } else {
                    *hp = f2b(hnew);
                }
            }
        }
    }

    if (doDec) {
        __syncthreads();   // all waves done reading Bl
        int g32 = w*4 + (l >> 4);
        #pragma unroll
        for (int j = 0; j < 4; j++) {
            int nl = j*16 + l16;
            part[nl*33 + g32] = pj[j];
        }
        __syncthreads();
        if (tid < 64) {
            float s = db[0];
            #pragma unroll
            for (int g = 0; g < 32; g++) s += part[tid*33 + g];
            outp[n0 + tid] = s;
        }
    }
}

extern "C" void kernel_launch(void* const* d_in, const int* in_sizes, int n_in,
                              void* d_out, int out_size, void* d_ws, size_t ws_size,
                              hipStream_t stream) {
    (void)in_sizes; (void)n_in; (void)out_size; (void)ws_size;
    const float* x    = (const float*)d_in[0];
    const float* ew   = (const float*)d_in[1];
    const float* ldt  = (const float*)d_in[2];
    const float* Cp   = (const float*)d_in[3];
    const float* lAr  = (const float*)d_in[4];
    const float* Aimp = (const float*)d_in[5];
    const float* Dsk  = (const float*)d_in[6];
    const float* outw = (const float*)d_in[7];
    const float* outb = (const float*)d_in[8];
    const float* dw   = (const float*)d_in[9];
    const float* db   = (const float*)d_in[10];

    float* ws = (float*)d_ws;
    unsigned short* hb  = (unsigned short*)ws;                  // 33,554,432 bf16  [h][b][l]
    unsigned short* Ybf = (unsigned short*)(ws + 16777216UL);   // 33,554,432 bf16
    unsigned short* AstB= (unsigned short*)(ws + 33554432UL);   //  8,388,608 bf16
    unsigned short* AcvB= (unsigned short*)(ws + 37748736UL);   // 25,165,824 bf16
    unsigned short* Wbf = (unsigned short*)(ws + 50331648UL);   //    524,288 bf16
    float* pdta = ws + 50593792UL;                              //     65,536 f32
    float* pwlc = ws + 50659328UL;                              //     65,536 f32
    float* pcd2 = ws + 50724864UL;                              //     65,536 f32  end ~203 MB

    k_prep1<<<128, 256, 0, stream>>>(ldt, Cp, lAr, Aimp, pdta, pwlc, pcd2);
    k_setup<<<7168, 256, 0, stream>>>(x, ew, hb, pdta, pcd2, AstB, AcvB, outw, Wbf);
    for (int layer = 0; layer < NLAY; layer++) {
        k_BG<<<4096, 256, 0, stream>>>(AstB + (size_t)layer*2097152,
                                       AcvB + (size_t)layer*6291456, hb,
                                       pwlc + layer*16384, pcd2 + layer*16384,
                                       Dsk + layer*HH, Ybf);
        k_gC2<<<2048, 512, 0, stream>>>(Wbf + layer*131072, outb + layer*512, Ybf, hb,
                                        dw, db, (float*)d_out, (layer == NLAY-1) ? 1 : 0);
    }
}